// Round 12
// baseline (241.273 us; speedup 1.0000x reference)
//
#include <hip/hip_runtime.h>
#include <hip/hip_bf16.h>
#include <stdint.h>

#define NV   65536   // active voxels
#define KOFF 27      // kernel offsets
#define CIN  128
#define COUT 128
#define NSEC (NV + 128)   // nbr_t per-offset stride (16B-aligned, holds dummy slot)

typedef __bf16 bf16x8 __attribute__((ext_vector_type(8)));
typedef float  f32x4  __attribute__((ext_vector_type(4)));

__device__ __forceinline__ void async_copy16(void* lds, const void* g) {
    __builtin_amdgcn_global_load_lds(
        (const __attribute__((address_space(1))) void*)g,
        (__attribute__((address_space(3))) void*)lds,
        16, 0, 0);
}

// ---- fused prep kernel (R11: guarded transposed scatter) -----------------
#define JOB_A_BLOCKS 4097
#define JOB_B_BLOCKS 216    // 27*4*4*2*64 chunks / 256
#define JOB_S_BLOCKS 1728   // 27*65536/4/256

__global__ void k_prep_all(const float* __restrict__ f,
                           uint4* __restrict__ fb4,
                           const float* __restrict__ w,
                           uint4* __restrict__ wfrag4,
                           const int4* __restrict__ in4,
                           const int4* __restrict__ out4,
                           int* __restrict__ nbr) {
    const int b = blockIdx.x;
    const int t = threadIdx.x;
    if (b < JOB_A_BLOCKS) {
        int i = b * 256 + t;
        int total8  = (NV + 1) * CIN / 8;
        int nvalid8 = NV * CIN / 8;
        if (i >= total8) return;
        union { uint4 u; __hip_bfloat16 h[8]; } p;
        if (i < nvalid8) {
            const float4* f4 = (const float4*)f;
            float4 a = f4[i * 2];
            float4 c = f4[i * 2 + 1];
            p.h[0] = __float2bfloat16(a.x);
            p.h[1] = __float2bfloat16(a.y);
            p.h[2] = __float2bfloat16(a.z);
            p.h[3] = __float2bfloat16(a.w);
            p.h[4] = __float2bfloat16(c.x);
            p.h[5] = __float2bfloat16(c.y);
            p.h[6] = __float2bfloat16(c.z);
            p.h[7] = __float2bfloat16(c.w);
        } else {
            p.u = make_uint4(0, 0, 0, 0);
        }
        fb4[i] = p.u;
    } else if (b < JOB_A_BLOCKS + JOB_B_BLOCKS) {
        int c    = (b - JOB_A_BLOCKS) * 256 + t;
        int lane = c & 63;
        int nt   = (c >> 6) & 1;
        int ks   = (c >> 7) & 3;
        int wv   = (c >> 9) & 3;
        int k    = c >> 11;
        int cout = wv * 32 + nt * 16 + (lane & 15);
        int cin0 = ks * 32 + (lane >> 4) * 8;
        const float* wk = w + k * 16384;
        union { uint4 u; __hip_bfloat16 h[8]; } p;
        #pragma unroll
        for (int j = 0; j < 8; ++j)
            p.h[j] = __float2bfloat16(wk[(cin0 + j) * 128 + cout]);
        wfrag4[c] = p.u;
    } else {
        int i = (b - JOB_A_BLOCKS - JOB_B_BLOCKS) * 256 + t;
        int k = i >> 14;
        int4 ii = in4[i];
        int4 oo = out4[i];
        int* nb = nbr + (size_t)k * NSEC;
        auto POS = [](int o) {
            return (o >> 7) * 128 + (o & 15) * 8 + ((o >> 4) & 7);
        };
        // transposed scatter, VALID PAIRS ONLY (padding -> no store;
        // sentinel comes from the memset)
        if ((unsigned)oo.x < NV) nb[POS(oo.x)] = ii.x;
        if ((unsigned)oo.y < NV) nb[POS(oo.y)] = ii.y;
        if ((unsigned)oo.z < NV) nb[POS(oo.z)] = ii.z;
        if ((unsigned)oo.w < NV) nb[POS(oo.w)] = ii.w;
    }
}

// ---- main gather-GEMM kernel -------------------------------------------
// 3-BLOCKS/CU residency test with per-work traffic BYTE-IDENTICAL to R4.
// Single 32 KB A buffer + T14 reg-staged prefetch: stage A(k+1) into 8
// uint4 VGPRs during compute(k) (issue-early), then vmcnt(10) + barrier +
// ds_write + barrier (write-late). LDS 64->32 KB unlocks 3 blocks/CU
// (12 waves, 3 independent barrier domains) at launch_bounds(256,3).
// R4's stall model: ~2600 cyc/offset of memory-wait not covered by MFMA
// with 8 lockstep waves; 12 waves in 3 domains should cover ~half of it.
// B: R10-proven in-place bcur[4][2] rotate (no spill). nbr: transposed
// int4 (R4). Everything per-work identical to R4.
__global__ __launch_bounds__(256, 3)
void sp_conv_main(const __hip_bfloat16* __restrict__ feats,
                  const uint4* __restrict__ wfrag,
                  const int* __restrict__ nbrt,
                  const float* __restrict__ bias,
                  float* __restrict__ out) {
    __shared__ unsigned char smem[32768];   // ONE 32 KB A buffer

    const int t   = threadIdx.x;
    const int bid = blockIdx.x;
    // XCD swizzle: consecutive 64-tile ranges per XCD (512 % 8 == 0)
    const int tile0 = ((bid & 7) * 64 + (bid >> 3)) * 128;

    const int w    = t >> 6;
    const int lane = t & 63;
    const int lr   = lane & 15;
    const int quad = lane >> 4;

    // staging XOR map (R4): LDS slot (row=i*16+srow, phys chunk t&15) holds
    // global chunk (t&15)^(row&15) -> conflict-free ds_read_b128
    const int srow  = t >> 4;
    const int sbyte = ((t & 15) ^ srow) * 16;

    f32x4 acc[8][2] = {};   // 64 VGPRs
    uint4 bcur[4][2];       // 16 VGPRs, rotated in place
    uint4 sreg[8];          // 32 VGPRs, reg-staged A(k+1)
    int   arows[8];

    const unsigned char* featsB = (const unsigned char*)feats;

    auto NLOAD = [&](int k) {   // 2 x int4 (transposed rulebook)
        const int4* np = (const int4*)(nbrt + (size_t)k * NSEC + tile0 + srow * 8);
        int4 a0 = np[0];
        int4 a1 = np[1];
        arows[0] = a0.x; arows[1] = a0.y; arows[2] = a0.z; arows[3] = a0.w;
        arows[4] = a1.x; arows[5] = a1.y; arows[6] = a1.z; arows[7] = a1.w;
    };
    auto SLOAD = [&]() {        // issue A(k+1) global->reg (8 x dwordx4)
        #pragma unroll
        for (int i = 0; i < 8; ++i) {
            unsigned ar = min((unsigned)arows[i], (unsigned)NV);
            sreg[i] = *(const uint4*)(featsB + (size_t)ar * 256 + sbyte);
        }
    };
    auto AFLOAD = [&](int ks, bf16x8 (&af)[8]) {
        #pragma unroll
        for (int mt = 0; mt < 8; ++mt)
            af[mt] = *(const bf16x8*)(smem + (mt * 16 + lr) * 256 +
                                      (((ks * 4 + quad) ^ lr) * 16));
    };
    auto MFMA16 = [&](bf16x8 (&af)[8], uint4 (&b)[2]) {
        #pragma unroll
        for (int mt = 0; mt < 8; ++mt)
            #pragma unroll
            for (int nt = 0; nt < 2; ++nt)
                acc[mt][nt] = __builtin_amdgcn_mfma_f32_16x16x32_bf16(
                    af[mt], *(const bf16x8*)&b[nt], acc[mt][nt], 0, 0, 0);
    };

    // ---- prologue: nbr(0) -> gload_lds A(0) -> nbr(1) + B(0) ----
    NLOAD(0);
    #pragma unroll
    for (int i = 0; i < 8; ++i) {
        unsigned ar = min((unsigned)arows[i], (unsigned)NV);
        async_copy16(smem + i * 4096 + t * 16,
                     featsB + (size_t)ar * 256 + sbyte);
    }
    __builtin_amdgcn_sched_barrier(0);   // staging oldest in vm queue
    NLOAD(1);
    {
        const uint4* wf0 = wfrag + w * 512 + lane;
        #pragma unroll
        for (int ks = 0; ks < 4; ++ks)
            #pragma unroll
            for (int nt = 0; nt < 2; ++nt)
                bcur[ks][nt] = wf0[ks * 128 + nt * 64];
    }
    asm volatile("s_waitcnt vmcnt(10)" ::: "memory");   // A(0) staged
    __builtin_amdgcn_s_barrier();
    __builtin_amdgcn_sched_barrier(0);

    // ---- one offset (single buffer, 2 barriers) ----
    auto ITER = [&](int k) {
        // issue-early: A(k+1) -> regs (oldest in vm queue)
        SLOAD();
        __builtin_amdgcn_sched_barrier(0);
        NLOAD(min(k + 2, KOFF - 1));
        const uint4* wfn = wfrag + (k + 1) * 2048 + w * 512 + lane;
        // compute k; refill bcur[ks] in place right after its last use
        #pragma unroll
        for (int ks = 0; ks < 4; ++ks) {
            bf16x8 af[8];
            AFLOAD(ks, af);
            __builtin_amdgcn_s_setprio(1);
            MFMA16(af, bcur[ks]);
            __builtin_amdgcn_s_setprio(0);
            bcur[ks][0] = wfn[ks * 128];
            bcur[ks][1] = wfn[ks * 128 + 64];
        }
        __builtin_amdgcn_sched_barrier(0);
        // sreg loads complete (10 younger: 2 nbr + 8 B); B/nbr stay in flight
        asm volatile("s_waitcnt vmcnt(10)" ::: "memory");
        __builtin_amdgcn_s_barrier();        // all waves done READING smem
        // write-late: A(k+1) -> smem (XOR map)
        #pragma unroll
        for (int i = 0; i < 8; ++i)
            *(uint4*)(smem + i * 4096 + t * 16) = sreg[i];
        asm volatile("s_waitcnt lgkmcnt(0)" ::: "memory");
        __builtin_amdgcn_s_barrier();        // writes visible to all
        __builtin_amdgcn_sched_barrier(0);
    };

    #pragma unroll 1
    for (int k = 0; k < KOFF - 1; ++k) ITER(k);

    // ---- tail k=26: bcur holds B(26); no loads/barriers ----
    #pragma unroll
    for (int ks = 0; ks < 4; ++ks) {
        bf16x8 af[8];
        AFLOAD(ks, af);
        MFMA16(af, bcur[ks]);
    }

    // ---- epilogue: C/D layout col = lane&15, row = quad*4 + reg ----
    const int n0w = w * 32;
    float bv[2];
    #pragma unroll
    for (int nt = 0; nt < 2; ++nt) bv[nt] = bias[n0w + nt * 16 + lr];

    #pragma unroll
    for (int mt = 0; mt < 8; ++mt) {
        #pragma unroll
        for (int nt = 0; nt < 2; ++nt) {
            #pragma unroll
            for (int r = 0; r < 4; ++r) {
                int grow = tile0 + mt * 16 + quad * 4 + r;
                out[(size_t)grow * COUT + n0w + nt * 16 + lr] =
                    acc[mt][nt][r] + bv[nt];
            }
        }
    }
}

// ---- launch -------------------------------------------------------------

extern "C" void kernel_launch(void* const* d_in, const int* in_sizes, int n_in,
                              void* d_out, int out_size, void* d_ws, size_t ws_size,
                              hipStream_t stream) {
    const float* features = (const float*)d_in[0];   // [N,128] f32
    const float* weight   = (const float*)d_in[1];   // [27,128,128] f32
    const float* bias     = (const float*)d_in[2];   // [128] f32
    const int*   in_idx   = (const int*)d_in[3];     // [27,N] i32
    const int*   out_idx  = (const int*)d_in[4];     // [27,N] i32
    float* out = (float*)d_out;                      // [N,128] f32

    uint8_t* ws = (uint8_t*)d_ws;
    size_t off = 0;
    __hip_bfloat16* feats_bf = (__hip_bfloat16*)(ws + off);       // (N+1)*256 B
    off += (size_t)(NV + 1) * CIN * 2;
    off = (off + 255) & ~(size_t)255;
    uint4* wfrag = (uint4*)(ws + off);                            // 27*2048*16 B
    off += (size_t)KOFF * CIN * COUT * 2;
    off = (off + 255) & ~(size_t)255;
    int* nbr = (int*)(ws + off);                                  // 27*NSEC*4 (transposed)

    // init nbr_t to 0xFFFFFFFF (-1 = "no neighbor"; main clamps to zero row)
    hipMemsetAsync(nbr, 0xFF, (size_t)KOFF * NSEC * 4, stream);

    // fused prep: feature cast + weight fragment-permute + rulebook scatter
    k_prep_all<<<JOB_A_BLOCKS + JOB_B_BLOCKS + JOB_S_BLOCKS, 256, 0, stream>>>(
        features, (uint4*)feats_bf, weight, wfrag,
        (const int4*)in_idx, (const int4*)out_idx, nbr);

    // main gather-GEMM: 512 tiles of 128 rows
    sp_conv_main<<<NV / 128, 256, 0, stream>>>(feats_bf, wfrag, nbr, bias, out);
}

// Round 13
// 157.540 us; speedup vs baseline: 1.5315x; 1.5315x over previous
//
#include <hip/hip_runtime.h>
#include <hip/hip_bf16.h>
#include <stdint.h>

#define NV   65536   // active voxels
#define KOFF 27      // kernel offsets
#define CIN  128
#define COUT 128
#define NSEC (NV + 128)   // nbr_t per-offset stride (16B-aligned, holds dummy slot)

typedef __bf16 bf16x8 __attribute__((ext_vector_type(8)));
typedef float  f32x16 __attribute__((ext_vector_type(16)));

__device__ __forceinline__ void async_copy16(void* lds, const void* g) {
    __builtin_amdgcn_global_load_lds(
        (const __attribute__((address_space(1))) void*)g,
        (__attribute__((address_space(3))) void*)lds,
        16, 0, 0);
}

// ---- fused prep kernel --------------------------------------------------
// Job B: weight -> fragment-major for mfma_f32_32x32x16_bf16:
//   chunk c = k*2048 + wv*512 + ks*64 + lane holds 8 bf16 =
//   B[cin = ks*16 + (lane>>5)*8 + j][cout = wv*32 + (lane&31)]
// Job S: guarded transposed scatter (R11-proven).
#define JOB_A_BLOCKS 4097
#define JOB_B_BLOCKS 216    // 27*2048 chunks / 256
#define JOB_S_BLOCKS 1728   // 27*65536/4/256

__global__ void k_prep_all(const float* __restrict__ f,
                           uint4* __restrict__ fb4,
                           const float* __restrict__ w,
                           uint4* __restrict__ wfrag4,
                           const int4* __restrict__ in4,
                           const int4* __restrict__ out4,
                           int* __restrict__ nbr) {
    const int b = blockIdx.x;
    const int t = threadIdx.x;
    if (b < JOB_A_BLOCKS) {
        int i = b * 256 + t;
        int total8  = (NV + 1) * CIN / 8;
        int nvalid8 = NV * CIN / 8;
        if (i >= total8) return;
        union { uint4 u; __hip_bfloat16 h[8]; } p;
        if (i < nvalid8) {
            const float4* f4 = (const float4*)f;
            float4 a = f4[i * 2];
            float4 c = f4[i * 2 + 1];
            p.h[0] = __float2bfloat16(a.x);
            p.h[1] = __float2bfloat16(a.y);
            p.h[2] = __float2bfloat16(a.z);
            p.h[3] = __float2bfloat16(a.w);
            p.h[4] = __float2bfloat16(c.x);
            p.h[5] = __float2bfloat16(c.y);
            p.h[6] = __float2bfloat16(c.z);
            p.h[7] = __float2bfloat16(c.w);
        } else {
            p.u = make_uint4(0, 0, 0, 0);
        }
        fb4[i] = p.u;
    } else if (b < JOB_A_BLOCKS + JOB_B_BLOCKS) {
        int c    = (b - JOB_A_BLOCKS) * 256 + t;   // chunk index
        int lane = c & 63;
        int ks   = (c >> 6) & 7;
        int wv   = (c >> 9) & 3;
        int k    = c >> 11;
        int cout = wv * 32 + (lane & 31);
        int cin0 = ks * 16 + (lane >> 5) * 8;
        const float* wk = w + k * 16384;
        union { uint4 u; __hip_bfloat16 h[8]; } p;
        #pragma unroll
        for (int j = 0; j < 8; ++j)
            p.h[j] = __float2bfloat16(wk[(cin0 + j) * 128 + cout]);
        wfrag4[c] = p.u;
    } else {
        int i = (b - JOB_A_BLOCKS - JOB_B_BLOCKS) * 256 + t;
        int k = i >> 14;
        int4 ii = in4[i];
        int4 oo = out4[i];
        int* nb = nbr + (size_t)k * NSEC;
        auto POS = [](int o) {
            return (o >> 7) * 128 + (o & 15) * 8 + ((o >> 4) & 7);
        };
        // transposed scatter, VALID PAIRS ONLY (sentinel from memset)
        if ((unsigned)oo.x < NV) nb[POS(oo.x)] = ii.x;
        if ((unsigned)oo.y < NV) nb[POS(oo.y)] = ii.y;
        if ((unsigned)oo.z < NV) nb[POS(oo.z)] = ii.z;
        if ((unsigned)oo.w < NV) nb[POS(oo.w)] = ii.w;
    }
}

// ---- main gather-GEMM kernel -------------------------------------------
// R4 structure with the MFMA SHAPE as the only change: 32x32x16 (issue
// 2066 vs 2483 cyc/SIMD/offset, -17%) at IDENTICAL geometry (wave = 128
// rows x 32 cols: 4 row-tiles of 32, 8 K-steps), identical LDS bytes
// (32 ds_read_b128/wave/offset), identical staging/nbr/B traffic,
// identical barrier cadence. Isolates the shape from R8's geometry
// confound. bA/bB = uint4[8] each (64 regs total), ~140 VGPR, no spill.
__global__ __launch_bounds__(256, 2)
void sp_conv_main(const __hip_bfloat16* __restrict__ feats,
                  const uint4* __restrict__ wfrag,
                  const int* __restrict__ nbrt,
                  const float* __restrict__ bias,
                  float* __restrict__ out) {
    __shared__ unsigned char smem[65536];   // two 32 KB A buffers

    const int t   = threadIdx.x;
    const int bid = blockIdx.x;
    // XCD swizzle: consecutive 64-tile ranges per XCD (512 % 8 == 0)
    const int tile0 = ((bid & 7) * 64 + (bid >> 3)) * 128;

    const int w    = t >> 6;
    const int lane = t & 63;
    const int lr   = lane & 15;
    const int l31  = lane & 31;
    const int part = lane >> 5;    // K-half within fragment

    // staging XOR map (R4): LDS slot (row=i*16+srow, phys chunk t&15) holds
    // global chunk (t&15)^(row&15)
    const int srow  = t >> 4;
    const int sbyte = ((t & 15) ^ srow) * 16;

    f32x16 acc[4] = {};     // 64 VGPRs
    uint4 bA[8], bB[8];     // 32+32 VGPRs (role-swapped)
    int   arows[8];

    const unsigned char* featsB = (const unsigned char*)feats;

    auto NLOAD = [&](int k) {   // 2 x int4 (transposed rulebook, R4-proven)
        const int4* np = (const int4*)(nbrt + (size_t)k * NSEC + tile0 + srow * 8);
        int4 a0 = np[0];
        int4 a1 = np[1];
        arows[0] = a0.x; arows[1] = a0.y; arows[2] = a0.z; arows[3] = a0.w;
        arows[4] = a1.x; arows[5] = a1.y; arows[6] = a1.z; arows[7] = a1.w;
    };
    auto STAGE = [&](int sb) {
        #pragma unroll
        for (int i = 0; i < 8; ++i) {
            unsigned ar = min((unsigned)arows[i], (unsigned)NV);
            async_copy16(smem + sb + i * 4096 + t * 16,
                         featsB + (size_t)ar * 256 + sbyte);
        }
    };
    auto BLOAD = [&](const uint4* wfk, uint4 (&b)[8]) {
        #pragma unroll
        for (int ks = 0; ks < 8; ++ks) b[ks] = wfk[ks * 64];
    };
    // A frag (ks): lane reads row = mt*32 + l31, global chunk ks*2+part,
    // phys chunk (ks*2+part)^(row&15); row&15 == lr
    auto AFLOAD = [&](int rb, int ks, bf16x8 (&af)[4]) {
        #pragma unroll
        for (int mt = 0; mt < 4; ++mt)
            af[mt] = *(const bf16x8*)(smem + rb + (mt * 32 + l31) * 256 +
                                      (((ks * 2 + part) ^ lr) << 4));
    };
    auto MFMA4 = [&](bf16x8 (&af)[4], uint4& b) {
        #pragma unroll
        for (int mt = 0; mt < 4; ++mt)
            acc[mt] = __builtin_amdgcn_mfma_f32_32x32x16_bf16(
                af[mt], *(const bf16x8*)&b, acc[mt], 0, 0, 0);
    };

    // ---- prologue: nbr(0) -> stage A0 -> nbr(1) + B(0) ----
    NLOAD(0);
    STAGE(0);
    __builtin_amdgcn_sched_barrier(0);   // staging ops oldest in vm queue
    NLOAD(1);
    BLOAD(wfrag + w * 512 + lane, bA);
    // 10 younger vm ops (2 nbr + 8 B) -> staging A0 guaranteed complete
    asm volatile("s_waitcnt vmcnt(10)" ::: "memory");
    __builtin_amdgcn_s_barrier();
    __builtin_amdgcn_sched_barrier(0);

    // ---- one offset; buse consumed, bload prefilled for k+1 ----
    auto ITER = [&](int k, int rb, uint4 (&buse)[8], uint4 (&bload)[8]) {
        STAGE(rb ^ 32768);
        __builtin_amdgcn_sched_barrier(0);
        NLOAD(min(k + 2, KOFF - 1));   // dup at k=25 harmless
        BLOAD(wfrag + (k + 1) * 2048 + w * 512 + lane, bload);
        // compute on buf rb with buse (no VMEM ops in here)
        #pragma unroll
        for (int ks = 0; ks < 8; ++ks) {
            bf16x8 af[4];
            AFLOAD(rb, ks, af);
            __builtin_amdgcn_s_setprio(1);
            MFMA4(af, buse[ks]);
            __builtin_amdgcn_s_setprio(0);
        }
        __builtin_amdgcn_sched_barrier(0);
        // own 8 staging loads complete; 10 nbr/B stay in flight (T4)
        asm volatile("s_waitcnt vmcnt(10)" ::: "memory");
        __builtin_amdgcn_s_barrier();
        __builtin_amdgcn_sched_barrier(0);
    };

    #pragma unroll 1
    for (int kk = 0; kk < KOFF - 1; kk += 2) {
        ITER(kk,     0,     bA, bB);   // even k: read buf0, stage buf1
        ITER(kk + 1, 32768, bB, bA);   // odd  k: read buf1, stage buf0
    }

    // ---- tail k=26: read buf0 with bA; no staging, no barriers ----
    #pragma unroll
    for (int ks = 0; ks < 8; ++ks) {
        bf16x8 af[4];
        AFLOAD(0, ks, af);
        MFMA4(af, bA[ks]);
    }

    // ---- epilogue: 32x32 C/D map: col = lane&31,
    //      row = (reg&3) + 8*(reg>>2) + 4*part ----
    const float bv = bias[w * 32 + l31];

    #pragma unroll
    for (int mt = 0; mt < 4; ++mt) {
        #pragma unroll
        for (int r = 0; r < 16; ++r) {
            int grow = tile0 + mt * 32 + (r & 3) + 8 * (r >> 2) + 4 * part;
            out[(size_t)grow * COUT + w * 32 + l31] = acc[mt][r] + bv;
        }
    }
}

// ---- launch -------------------------------------------------------------

extern "C" void kernel_launch(void* const* d_in, const int* in_sizes, int n_in,
                              void* d_out, int out_size, void* d_ws, size_t ws_size,
                              hipStream_t stream) {
    const float* features = (const float*)d_in[0];   // [N,128] f32
    const float* weight   = (const float*)d_in[1];   // [27,128,128] f32
    const float* bias     = (const float*)d_in[2];   // [128] f32
    const int*   in_idx   = (const int*)d_in[3];     // [27,N] i32
    const int*   out_idx  = (const int*)d_in[4];     // [27,N] i32
    float* out = (float*)d_out;                      // [N,128] f32

    uint8_t* ws = (uint8_t*)d_ws;
    size_t off = 0;
    __hip_bfloat16* feats_bf = (__hip_bfloat16*)(ws + off);       // (N+1)*256 B
    off += (size_t)(NV + 1) * CIN * 2;
    off = (off + 255) & ~(size_t)255;
    uint4* wfrag = (uint4*)(ws + off);                            // 27*2048*16 B
    off += (size_t)KOFF * CIN * COUT * 2;
    off = (off + 255) & ~(size_t)255;
    int* nbr = (int*)(ws + off);                                  // 27*NSEC*4 (transposed)

    // init nbr_t to 0xFFFFFFFF (-1 = "no neighbor"; main clamps to zero row)
    hipMemsetAsync(nbr, 0xFF, (size_t)KOFF * NSEC * 4, stream);

    // fused prep: feature cast + weight fragment-permute + rulebook scatter
    k_prep_all<<<JOB_A_BLOCKS + JOB_B_BLOCKS + JOB_S_BLOCKS, 256, 0, stream>>>(
        features, (uint4*)feats_bf, weight, wfrag,
        (const int4*)in_idx, (const int4*)out_idx, nbr);

    // main gather-GEMM: 512 tiles of 128 rows
    sp_conv_main<<<NV / 128, 256, 0, stream>>>(feats_bf, wfrag, nbr, bias, out);
}

// Round 14
// 150.208 us; speedup vs baseline: 1.6063x; 1.0488x over previous
//
#include <hip/hip_runtime.h>
#include <hip/hip_bf16.h>
#include <stdint.h>

#define NV   65536   // active voxels
#define KOFF 27      // kernel offsets
#define CIN  128
#define COUT 128
#define NSEC (NV + 128)   // nbr_t per-offset stride (16B-aligned, holds dummy slot)

typedef __bf16 bf16x8 __attribute__((ext_vector_type(8)));
typedef float  f32x4  __attribute__((ext_vector_type(4)));

__device__ __forceinline__ void async_copy16(void* lds, const void* g) {
    __builtin_amdgcn_global_load_lds(
        (const __attribute__((address_space(1))) void*)g,
        (__attribute__((address_space(3))) void*)lds,
        16, 0, 0);
}

// ---- fused prep kernel (R11: guarded transposed scatter) -----------------
// Job S: ~1.07M padded pairs carry out_idx = N; storing them all to the
// same dummy slot was a million-way same-address serialization (Guideline
// 12). Sentinel comes from the memset; dummy slot is never read -> guard.
#define JOB_A_BLOCKS 4097
#define JOB_B_BLOCKS 216    // 27*4*4*2*64 chunks / 256
#define JOB_S_BLOCKS 1728   // 27*65536/4/256

__global__ void k_prep_all(const float* __restrict__ f,
                           uint4* __restrict__ fb4,
                           const float* __restrict__ w,
                           uint4* __restrict__ wfrag4,
                           const int4* __restrict__ in4,
                           const int4* __restrict__ out4,
                           int* __restrict__ nbr) {
    const int b = blockIdx.x;
    const int t = threadIdx.x;
    if (b < JOB_A_BLOCKS) {
        int i = b * 256 + t;
        int total8  = (NV + 1) * CIN / 8;
        int nvalid8 = NV * CIN / 8;
        if (i >= total8) return;
        union { uint4 u; __hip_bfloat16 h[8]; } p;
        if (i < nvalid8) {
            const float4* f4 = (const float4*)f;
            float4 a = f4[i * 2];
            float4 c = f4[i * 2 + 1];
            p.h[0] = __float2bfloat16(a.x);
            p.h[1] = __float2bfloat16(a.y);
            p.h[2] = __float2bfloat16(a.z);
            p.h[3] = __float2bfloat16(a.w);
            p.h[4] = __float2bfloat16(c.x);
            p.h[5] = __float2bfloat16(c.y);
            p.h[6] = __float2bfloat16(c.z);
            p.h[7] = __float2bfloat16(c.w);
        } else {
            p.u = make_uint4(0, 0, 0, 0);
        }
        fb4[i] = p.u;
    } else if (b < JOB_A_BLOCKS + JOB_B_BLOCKS) {
        int c    = (b - JOB_A_BLOCKS) * 256 + t;
        int lane = c & 63;
        int nt   = (c >> 6) & 1;
        int ks   = (c >> 7) & 3;
        int wv   = (c >> 9) & 3;
        int k    = c >> 11;
        int cout = wv * 32 + nt * 16 + (lane & 15);
        int cin0 = ks * 32 + (lane >> 4) * 8;
        const float* wk = w + k * 16384;
        union { uint4 u; __hip_bfloat16 h[8]; } p;
        #pragma unroll
        for (int j = 0; j < 8; ++j)
            p.h[j] = __float2bfloat16(wk[(cin0 + j) * 128 + cout]);
        wfrag4[c] = p.u;
    } else {
        int i = (b - JOB_A_BLOCKS - JOB_B_BLOCKS) * 256 + t;
        int k = i >> 14;
        int4 ii = in4[i];
        int4 oo = out4[i];
        int* nb = nbr + (size_t)k * NSEC;
        auto POS = [](int o) {
            return (o >> 7) * 128 + (o & 15) * 8 + ((o >> 4) & 7);
        };
        // transposed scatter, VALID PAIRS ONLY (padding -> no store)
        if ((unsigned)oo.x < NV) nb[POS(oo.x)] = ii.x;
        if ((unsigned)oo.y < NV) nb[POS(oo.y)] = ii.y;
        if ((unsigned)oo.z < NV) nb[POS(oo.z)] = ii.z;
        if ((unsigned)oo.w < NV) nb[POS(oo.w)] = ii.w;
    }
}

// ---- main gather-GEMM kernel (R4, proven 57.0 µs) -----------------------
// BM=128, 2 blocks/CU, wave = 128 rows x 32 cols, LDS double-buffer,
// transposed-nbr int4 loads, counted vmcnt(10), 1 barrier per offset.
// Structural plateau: ~5100 cyc/offset vs 2480-cyc MFMA floor, with MFMA
// issue / LDS service / L2 service all in the 2000-3000 cyc band; every
// single-axis variant (13 experiments) measured equal or worse.
__global__ __launch_bounds__(256, 2)
void sp_conv_main(const __hip_bfloat16* __restrict__ feats,
                  const uint4* __restrict__ wfrag,
                  const int* __restrict__ nbrt,
                  const float* __restrict__ bias,
                  float* __restrict__ out) {
    __shared__ unsigned char smem[65536];   // two 32 KB A buffers

    const int t   = threadIdx.x;
    const int bid = blockIdx.x;
    // XCD swizzle: consecutive 64-tile ranges per XCD (512 % 8 == 0, bijective)
    const int tile0 = ((bid & 7) * 64 + (bid >> 3)) * 128;

    const int w    = t >> 6;
    const int lane = t & 63;
    const int lr   = lane & 15;
    const int quad = lane >> 4;

    // staging-side XOR map: LDS slot (row = i*16 + srow, physchunk = t&15)
    // holds global 16B chunk (t&15) ^ (row&15) -> conflict-free ds_read_b128
    const int srow  = t >> 4;
    const int sbyte = ((t & 15) ^ srow) * 16;

    f32x4 acc[8][2] = {};  // 64 VGPRs

    const unsigned char* featsB = (const unsigned char*)feats;

    int  arows[8];
    uint4 bA[4][2], bB[4][2];   // [ks][nt] fragment regs (role-swapped)

    auto NLOAD = [&](int k) {   // 2 x int4: rows i*16+srow, i=0..7
        const int4* np = (const int4*)(nbrt + (size_t)k * NSEC + tile0 + srow * 8);
        int4 a0 = np[0];
        int4 a1 = np[1];
        arows[0] = a0.x; arows[1] = a0.y; arows[2] = a0.z; arows[3] = a0.w;
        arows[4] = a1.x; arows[5] = a1.y; arows[6] = a1.z; arows[7] = a1.w;
    };
    auto STAGE = [&](int sb) {
        #pragma unroll
        for (int i = 0; i < 8; ++i) {
            unsigned ar = min((unsigned)arows[i], (unsigned)NV);
            async_copy16(smem + sb + i * 4096 + t * 16,
                         featsB + (size_t)ar * 256 + sbyte);
        }
    };
    auto BLOAD = [&](const uint4* wfk, uint4 (&b)[4][2]) {
        #pragma unroll
        for (int ks = 0; ks < 4; ++ks)
            #pragma unroll
            for (int nt = 0; nt < 2; ++nt)
                b[ks][nt] = wfk[ks * 128 + nt * 64];
    };
    auto AFLOAD = [&](int rb, int ks, bf16x8 (&af)[8]) {
        #pragma unroll
        for (int mt = 0; mt < 8; ++mt)
            af[mt] = *(const bf16x8*)(smem + rb + (mt * 16 + lr) * 256 +
                                      (((ks * 4 + quad) ^ lr) * 16));
    };
    auto MFMA16 = [&](bf16x8 (&af)[8], uint4 (&b)[2]) {
        #pragma unroll
        for (int mt = 0; mt < 8; ++mt)
            #pragma unroll
            for (int nt = 0; nt < 2; ++nt)
                acc[mt][nt] = __builtin_amdgcn_mfma_f32_16x16x32_bf16(
                    af[mt], *(const bf16x8*)&b[nt], acc[mt][nt], 0, 0, 0);
    };

    // ---- prologue: nbr(0) -> stage A0 -> prefetch nbr(1), B(0) ----
    NLOAD(0);
    STAGE(0);
    __builtin_amdgcn_sched_barrier(0);   // staging ops oldest in vm queue
    NLOAD(1);
    BLOAD(wfrag + w * 512 + lane, bA);
    // 10 younger vm ops (2 nbr + 8 B) -> staging A0 guaranteed complete
    asm volatile("s_waitcnt vmcnt(10)" ::: "memory");
    __builtin_amdgcn_s_barrier();
    __builtin_amdgcn_sched_barrier(0);

    // ---- one offset; buse consumed, bload prefilled for k+1 ----
    auto ITER = [&](int k, int rb, uint4 (&buse)[4][2], uint4 (&bload)[4][2]) {
        // issue A(k+1) staging first (oldest), then nbr(k+2) + B(k+1)
        STAGE(rb ^ 32768);
        __builtin_amdgcn_sched_barrier(0);
        NLOAD(min(k + 2, KOFF - 1));   // dup at k=25 harmless
        BLOAD(wfrag + (k + 1) * 2048 + w * 512 + lane, bload);
        // compute on buf rb with buse (no VMEM ops in here)
        #pragma unroll
        for (int ks = 0; ks < 4; ++ks) {
            bf16x8 af[8];
            AFLOAD(rb, ks, af);
            __builtin_amdgcn_s_setprio(1);
            MFMA16(af, buse[ks]);
            __builtin_amdgcn_s_setprio(0);
        }
        __builtin_amdgcn_sched_barrier(0);
        // own 8 staging loads complete; 10 nbr/B stay in flight (T4)
        asm volatile("s_waitcnt vmcnt(10)" ::: "memory");
        __builtin_amdgcn_s_barrier();
        __builtin_amdgcn_sched_barrier(0);
    };

    #pragma unroll 1
    for (int kk = 0; kk < KOFF - 1; kk += 2) {
        ITER(kk,     0,     bA, bB);   // even k: read buf0, stage buf1
        ITER(kk + 1, 32768, bB, bA);   // odd  k: read buf1, stage buf0
    }

    // ---- tail k=26: read buf0 with bA; no staging, no barriers ----
    #pragma unroll
    for (int ks = 0; ks < 4; ++ks) {
        bf16x8 af[8];
        AFLOAD(0, ks, af);
        MFMA16(af, bA[ks]);
    }

    // ---- epilogue: C/D layout col = lane&15, row = quad*4 + reg ----
    const int n0w = w * 32;
    float bv[2];
    #pragma unroll
    for (int nt = 0; nt < 2; ++nt) bv[nt] = bias[n0w + nt * 16 + lr];

    #pragma unroll
    for (int mt = 0; mt < 8; ++mt) {
        #pragma unroll
        for (int nt = 0; nt < 2; ++nt) {
            #pragma unroll
            for (int r = 0; r < 4; ++r) {
                int grow = tile0 + mt * 16 + quad * 4 + r;
                out[(size_t)grow * COUT + n0w + nt * 16 + lr] =
                    acc[mt][nt][r] + bv[nt];
            }
        }
    }
}

// ---- launch -------------------------------------------------------------

extern "C" void kernel_launch(void* const* d_in, const int* in_sizes, int n_in,
                              void* d_out, int out_size, void* d_ws, size_t ws_size,
                              hipStream_t stream) {
    const float* features = (const float*)d_in[0];   // [N,128] f32
    const float* weight   = (const float*)d_in[1];   // [27,128,128] f32
    const float* bias     = (const float*)d_in[2];   // [128] f32
    const int*   in_idx   = (const int*)d_in[3];     // [27,N] i32
    const int*   out_idx  = (const int*)d_in[4];     // [27,N] i32
    float* out = (float*)d_out;                      // [N,128] f32

    uint8_t* ws = (uint8_t*)d_ws;
    size_t off = 0;
    __hip_bfloat16* feats_bf = (__hip_bfloat16*)(ws + off);       // (N+1)*256 B
    off += (size_t)(NV + 1) * CIN * 2;
    off = (off + 255) & ~(size_t)255;
    uint4* wfrag = (uint4*)(ws + off);                            // 27*2048*16 B
    off += (size_t)KOFF * CIN * COUT * 2;
    off = (off + 255) & ~(size_t)255;
    int* nbr = (int*)(ws + off);                                  // 27*NSEC*4 (transposed)

    // init nbr_t to 0xFFFFFFFF (-1 = "no neighbor"; main clamps to zero row)
    hipMemsetAsync(nbr, 0xFF, (size_t)KOFF * NSEC * 4, stream);

    // fused prep: feature cast + weight fragment-permute + rulebook scatter
    k_prep_all<<<JOB_A_BLOCKS + JOB_B_BLOCKS + JOB_S_BLOCKS, 256, 0, stream>>>(
        features, (uint4*)feats_bf, weight, wfrag,
        (const int4*)in_idx, (const int4*)out_idx, nbr);

    // main gather-GEMM: 512 tiles of 128 rows
    sp_conv_main<<<NV / 128, 256, 0, stream>>>(feats_bf, wfrag, nbr, bias, out);
}